// Round 10
// baseline (218.205 us; speedup 1.0000x reference)
//
#include <hip/hip_runtime.h>
#include <math.h>

#define E_LEN 512
#define C_CLS 14
#define BATCH 8192
#define NSLOTS 256
#define NBLK (BATCH / 8)
#define WS_G 256    // Gram offset in ws (floats)
#define WS_WB 464   // packed bf16 w offset in ws (dwords)
#define WB_ROW 260  // dwords per wB row
#define NCH 16      // K chunks of 32 e

typedef float v4f __attribute__((ext_vector_type(4)));
typedef short s8v __attribute__((ext_vector_type(8)));  // 8 bf16 (4 VGPRs)
union APk { int i[4]; s8v s; };

// f32 pair -> packed bf16 (RNE), gfx950 VOP3
#define CVT_PK_BF16(d, a, b) \
  asm("v_cvt_pk_bf16_f32 %0, %1, %2" : "=v"(d) : "v"(a), "v"(b))

// ---- cross-lane helpers (VALU-pipe DPP) ----
template<int CTRL>
__device__ __forceinline__ float dpp_mov_f(float v) {
  return __int_as_float(__builtin_amdgcn_update_dpp(
      0, __float_as_int(v), CTRL, 0xF, 0xF, false));
}
__device__ __forceinline__ float sum16(float v) {  // row16 sum (ror 8,4,2,1)
  v += dpp_mov_f<0x128>(v);
  v += dpp_mov_f<0x124>(v);
  v += dpp_mov_f<0x122>(v);
  v += dpp_mov_f<0x121>(v);
  return v;
}
// lane31 = sum(lanes 0..31), lane63 = sum(lanes 32..63)
__device__ __forceinline__ float hsum32(float v) {
  v = sum16(v);
  v += dpp_mov_f<0x142>(v);  // row_bcast15
  return v;
}
__device__ __forceinline__ float wsum64(float v) {
  v = sum16(v);
  v += dpp_mov_f<0x142>(v);
  v += dpp_mov_f<0x143>(v);
  return v;
}
template<int PAT>
__device__ __forceinline__ float swz_f(float v) {  // 32-lane-group swizzle
  return __int_as_float(__builtin_amdgcn_ds_swizzle(__float_as_int(v), PAT));
}
__device__ __forceinline__ float shfl_x32(float v) {
  return __shfl_xor(v, 32, 64);
}
__device__ __forceinline__ float softplus_f(float v) {
  return fmaxf(v, 0.f) + __logf(1.f + __expf(-fabsf(v)));
}

// ---- prep (1 block): zero slots, Gram G=w^T w (fp32), pack w -> bf16 rows
//      (LINEAR e-order: matches direct-load read order) ----
__global__ void MID_LOSS_prep(const float* __restrict__ w,
                              float* __restrict__ wsf) {
  __shared__ float wl[E_LEN * C_CLS];
  const int tid = threadIdx.x;
#pragma unroll
  for (int i = 0; i < 7; ++i)
    ((float4*)wl)[tid + i * 256] = ((const float4*)w)[tid + i * 256];
  wsf[tid] = 0.f;  // slots
  __syncthreads();
  if (tid < 196) {
    const int p = tid / 14, n = tid - p * 14;
    float g = 0.f;
    for (int e = 0; e < E_LEN; ++e)
      g = fmaf(wl[e * 14 + p], wl[e * 14 + n], g);
    wsf[WS_G + tid] = g;
  }
  // wB[c][e] bf16, c padded to 16 (zeros), row stride WB_ROW dwords
  unsigned int* wsu = (unsigned int*)wsf;
  for (int i = tid; i < 4096; i += 256) {
    const int c = i >> 8;        // 0..15
    const int ep = i & 255;      // e-pair
    const int e = ep * 2;
    const float v0 = (c < 14) ? wl[e * 14 + c] : 0.f;
    const float v1 = (c < 14) ? wl[(e + 1) * 14 + c] : 0.f;
    int d;
    CVT_PK_BF16(d, v0, v1);
    wsu[WS_WB + c * WB_ROW + ep] = (unsigned int)d;
  }
}

// ---- main: 1 block = 8 samples; DIRECT strided global->reg x loads with a
//      4-deep prefetch ring (3 chunks / ~6 KB per wave in flight -> ~3x the
//      in-flight bytes of all prior variants), MFMA core. Plain loads
//      (r3-proven path). launch_bounds(256,4): 128-VGPR budget
//      (r2 lesson: (256,8) spilled) ----
__global__ __launch_bounds__(256, 4)
void MID_LOSS_main(const float* __restrict__ x, const int* __restrict__ y,
                   const float* __restrict__ wsf, float* __restrict__ slots) {
  __shared__ unsigned int wB_l[16 * WB_ROW];  // 16.6 KB bf16 w
  __shared__ float G_l[196];
  __shared__ float dots_l[4][2][16];
  __shared__ float P_l[4][2][16];

  const int tid = threadIdx.x;
  const int lane = tid & 63;
  const int wid = tid >> 6;
  const unsigned int* wsu = (const unsigned int*)wsf;

  // stage packed w + Gram once per block (one barrier total)
  for (int i = tid; i < 16 * WB_ROW; i += 256) wB_l[i] = wsu[WS_WB + i];
  if (tid < 196) G_l[tid] = wsf[WS_G + tid];
  __syncthreads();

  // fragment geometry: A row = (sample, m), k-slice kg = lane>>4
  const int row = lane & 15;
  const int kg = lane >> 4;
  const int m = row & 7;
  const int b0 = blockIdx.x * 8 + wid * 2;  // this wave's 2 samples
  // per-lane x base: sample (b0 + slot), k-group kg, feature m
  const float* xl = x + (size_t)b0 * 4096 + (row >> 3) * 4096 + kg * 64 + m;
  const unsigned int* wrow = wB_l + row * WB_ROW;

  // hoist the y read (its latency hides under the K-loop)
  const int yv = (lane < 28) ? y[b0 * 14 + lane] : 0;

  v4f acc = {0.f, 0.f, 0.f, 0.f};   // dot C-tile
  v4f acc2 = {0.f, 0.f, 0.f, 0.f};  // Gram C-tile (A*A^T)
  float q = 0.f;                    // fp32 sum u^2 (this lane's slice)

  float u[4][8];  // 4-deep chunk ring; all indices static (full unroll)
#pragma unroll
  for (int c = 0; c < 3; ++c)
#pragma unroll
    for (int t = 0; t < 8; ++t)
      u[c][t] = xl[c * 256 + t * 8];

#pragma unroll
  for (int ch = 0; ch < NCH; ++ch) {
    const int cur = ch & 3;
    // issue chunk ch+3's 8 strided dwords (keep 3 chunks in flight)
    if (ch < NCH - 3) {
#pragma unroll
      for (int t = 0; t < 8; ++t)
        u[(ch + 3) & 3][t] = xl[(ch + 3) * 256 + t * 8];
    }
    const s8v bfrag = *(const s8v*)(wrow + ch * 16 + kg * 4);
#pragma unroll
    for (int t = 0; t < 8; ++t) q = fmaf(u[cur][t], u[cur][t], q);
    APk a;
#pragma unroll
    for (int jj = 0; jj < 4; ++jj)
      CVT_PK_BF16(a.i[jj], u[cur][2 * jj], u[cur][2 * jj + 1]);

    acc = __builtin_amdgcn_mfma_f32_16x16x32_bf16(a.s, bfrag, acc, 0, 0, 0);
    acc2 = __builtin_amdgcn_mfma_f32_16x16x32_bf16(a.s, a.s, acc2, 0, 0, 0);
  }

  // ---- stage P mask for the wave's 2 samples (same-wave, no barrier) ----
  if (lane < 28) {
    const int s = (lane >= 14) ? 1 : 0;
    P_l[wid][s][lane - s * 14] = (yv == 1) ? 1.f : 0.f;
  }

  // ---- dot tail: max over m (C layout: col=lane&15, row=kg*4+reg) ----
  float dmax = fmaxf(fmaxf(acc[0], acc[1]), fmaxf(acc[2], acc[3]));
  dmax = fmaxf(dmax, swz_f<0x401F>(dmax));  // xor16: combine kg pairs
  if ((lane & 16) == 0 && (lane & 15) < 14)
    dots_l[wid][lane >> 5][lane & 15] = dmax;

  // ---- Gram tail: per-sample 8x8 block sum (for l1) ----
  const float loc2 = acc2[0] + acc2[1] + acc2[2] + acc2[3];
  const bool validb = (((lane & 15) < 8) == (lane < 32));
  float s2v = validb ? loc2 : 0.f;
  float q2 = q + shfl_x32(q);
  float qv = validb ? q2 : 0.f;

  asm volatile("s_waitcnt lgkmcnt(0)" ::: "memory");  // dots/P visible in-wave

  // ---- pair phase: lanes 0-31 do b0's 196 pairs, lanes 32-63 do b1's ----
  const int half = lane >> 5;
  const int hl = lane & 31;
  const float* dp = dots_l[wid][half];
  const float* Pp = P_l[wid][half];
  float S = 0.f, Gc = 0.f;
#pragma unroll
  for (int r = 0; r < 7; ++r) {
    const int tt = r * 28 + hl;
    if (hl < 28) {
      const int p = (tt * 2341) >> 15;  // tt/14, exact for tt<196
      const int n = tt - p * 14;
      const float Ppv = Pp[p], Pnv = Pp[n];
      S += Ppv * (1.f - Pnv) * softplus_f(dp[n] - dp[p]);
      Gc = fmaf(Ppv * Pnv, G_l[tt], Gc);
    }
  }
  float npv = (hl < 14) ? Pp[hl] : 0.f;
  float w2v = (hl < 14) ? Pp[hl] * G_l[hl * 15] : 0.f;  // P[c]*G[c][c]

  // ---- six half-reductions: lane31 = b0 totals, lane63 = b1 totals ----
  S = hsum32(S);
  Gc = hsum32(Gc);
  s2v = hsum32(s2v);
  qv = hsum32(qv);
  npv = hsum32(npv);
  w2v = hsum32(w2v);

  float loss = 0.f;
  if ((lane & 31) == 31) {
    const float npos = npv;
    const float base = S / npos;  // nneg>=1 guaranteed (y[:,-1]=0)
    const float tv =
        (npos > 1.5f) ? (w2v - Gc / npos) / (npos - 1.f) : 0.f;
    // l1 = sum_e sig2 (var >= 0) = (sum u^2 - (1/8) sum_e t^2)/7
    const float l1 = (qv - s2v * 0.125f) * (1.f / 7.f);
    loss = 1.4f * (1.f + tv) * base + 0.6f * l1;  // 2*((1-b)(1+tv)base + b*l1)
  }
  loss += shfl_x32(loss);  // lane31 = b0+b1
  if (lane == 31) atomicAdd(&slots[blockIdx.x & (NSLOTS - 1)], loss);
}

// ---- finalize (1 wave): sum the 256 slots -> out[0] ----
__global__ void MID_LOSS_fin(const float* __restrict__ wsf,
                             float* __restrict__ out) {
  const int tid = threadIdx.x;  // 64 threads
  float s = wsf[tid] + wsf[tid + 64] + wsf[tid + 128] + wsf[tid + 192];
  s = wsum64(s);
  if (tid == 63) out[0] = s * (1.f / (float)BATCH);
}

extern "C" void kernel_launch(void* const* d_in, const int* in_sizes, int n_in,
                              void* d_out, int out_size, void* d_ws, size_t ws_size,
                              hipStream_t stream) {
  const float* x = (const float*)d_in[0];
  const int* y = (const int*)d_in[1];
  const float* w = (const float*)d_in[2];
  float* out = (float*)d_out;
  float* wsf = (float*)d_ws;

  MID_LOSS_prep<<<1, 256, 0, stream>>>(w, wsf);
  MID_LOSS_main<<<NBLK, 256, 0, stream>>>(x, y, wsf, wsf);
  MID_LOSS_fin<<<1, 64, 0, stream>>>(wsf, out);
}

// Round 11
// 206.723 us; speedup vs baseline: 1.0555x; 1.0555x over previous
//
#include <hip/hip_runtime.h>
#include <math.h>

#define E_LEN 512
#define C_CLS 14
#define BATCH 8192
#define NSLOTS 256
#define NBLK (BATCH / 8)
#define WS_G 256    // Gram offset in ws (floats)
#define WS_WB 464   // packed bf16 w offset in ws (dwords)
#define WB_ROW 260  // dwords per wB row
#define NCH 16      // K chunks of 32 e
#define XBUF 512    // dwords per buffer per wave (2 samples x 256)
#define XW 1024     // per-wave xs dwords (2 buffers)

typedef float v4f __attribute__((ext_vector_type(4)));
typedef short s8v __attribute__((ext_vector_type(8)));  // 8 bf16 (4 VGPRs)
union APk { int i[4]; s8v s; };

// f32 pair -> packed bf16 (RNE), gfx950 VOP3
#define CVT_PK_BF16(d, a, b) \
  asm("v_cvt_pk_bf16_f32 %0, %1, %2" : "=v"(d) : "v"(a), "v"(b))

// async global->LDS DMA, NT + SC1 (aux=18: CPol NT|SC1 on gfx940+):
// x is single-use streaming data -> skip L2 allocation entirely (SC1) and
// evict-first (NT); don't spend replacement work on 134 MB of one-shot lines
__device__ __forceinline__ void dma16nt(const float* gp, float* lp) {
  __builtin_amdgcn_global_load_lds(
      (const __attribute__((address_space(1))) void*)gp,
      (__attribute__((address_space(3))) void*)lp, 16, 0, 18);
}

// ---- cross-lane helpers (VALU-pipe DPP) ----
template<int CTRL>
__device__ __forceinline__ float dpp_mov_f(float v) {
  return __int_as_float(__builtin_amdgcn_update_dpp(
      0, __float_as_int(v), CTRL, 0xF, 0xF, false));
}
__device__ __forceinline__ float sum16(float v) {  // row16 sum (ror 8,4,2,1)
  v += dpp_mov_f<0x128>(v);
  v += dpp_mov_f<0x124>(v);
  v += dpp_mov_f<0x122>(v);
  v += dpp_mov_f<0x121>(v);
  return v;
}
// lane31 = sum(lanes 0..31), lane63 = sum(lanes 32..63)
__device__ __forceinline__ float hsum32(float v) {
  v = sum16(v);
  v += dpp_mov_f<0x142>(v);  // row_bcast15
  return v;
}
__device__ __forceinline__ float wsum64(float v) {
  v = sum16(v);
  v += dpp_mov_f<0x142>(v);
  v += dpp_mov_f<0x143>(v);
  return v;
}
template<int PAT>
__device__ __forceinline__ float swz_f(float v) {  // 32-lane-group swizzle
  return __int_as_float(__builtin_amdgcn_ds_swizzle(__float_as_int(v), PAT));
}
__device__ __forceinline__ float shfl_x32(float v) {
  return __shfl_xor(v, 32, 64);
}
__device__ __forceinline__ float softplus_f(float v) {
  return fmaxf(v, 0.f) + __logf(1.f + __expf(-fabsf(v)));
}

// ---- prep (1 block): zero slots, Gram G=w^T w (fp32), pack w bf16
//      with per-kg XOR k-permutation (compensates main's conflict-free
//      LDS read order j = t^kg; zero runtime cost) ----
__global__ void MID_LOSS_prep(const float* __restrict__ w,
                              float* __restrict__ wsf) {
  __shared__ float wl[E_LEN * C_CLS];
  const int tid = threadIdx.x;
#pragma unroll
  for (int i = 0; i < 7; ++i)
    ((float4*)wl)[tid + i * 256] = ((const float4*)w)[tid + i * 256];
  wsf[tid] = 0.f;  // slots
  __syncthreads();
  if (tid < 196) {
    const int p = tid / 14, n = tid - p * 14;
    float g = 0.f;
    for (int e = 0; e < E_LEN; ++e)
      g = fmaf(wl[e * 14 + p], wl[e * 14 + n], g);
    wsf[WS_G + tid] = g;
  }
  // wB[c][ep] bf16, c padded to 16 (zeros), row stride WB_ROW dwords.
  // ep = ch*16 + kg*4 + d; dword holds k-slots (2d, 2d+1) of kg-block,
  // whose VALUES are e = ch*32 + kg*8 + ((2d+s) ^ kg)  (XOR compensation)
  unsigned int* wsu = (unsigned int*)wsf;
  for (int i = tid; i < 4096; i += 256) {
    const int c = i >> 8;        // 0..15
    const int ep = i & 255;      // e-pair slot
    const int kg = (ep >> 2) & 3;
    const int d = ep & 3;
    const int eb = ((ep >> 4) << 5) + (kg << 3);
    const int e0 = eb + ((2 * d) ^ kg);
    const int e1 = eb + ((2 * d + 1) ^ kg);
    const float v0 = (c < 14) ? wl[e0 * 14 + c] : 0.f;
    const float v1 = (c < 14) ? wl[e1 * 14 + c] : 0.f;
    int dd;
    CVT_PK_BF16(dd, v0, v1);
    wsu[WS_WB + c * WB_ROW + ep] = (unsigned int)dd;
  }
}

// ---- main: 1 block = 8 samples; LINEAR 16B NT+SC1 global->LDS DMA
//      (2/chunk), conflict-free XOR-order LDS reads (B-side compensated in
//      prep), zero K-loop barriers, fine vmcnt pipeline, MFMA core ----
__global__ __launch_bounds__(256, 4)
void MID_LOSS_main(const float* __restrict__ x, const int* __restrict__ y,
                   const float* __restrict__ wsf, float* __restrict__ slots) {
  __shared__ unsigned int wB_l[16 * WB_ROW];  // 16.6 KB bf16 w
  __shared__ float G_l[196];
  __shared__ alignas(16) float xs[4 * XW];    // 16 KB wave-private x stage
  __shared__ float dots_l[4][2][16];
  __shared__ float P_l[4][2][16];

  const int tid = threadIdx.x;
  const int lane = tid & 63;
  const int wid = tid >> 6;
  const unsigned int* wsu = (const unsigned int*)wsf;

  // stage packed w + Gram once per block (one barrier total)
  for (int i = tid; i < 16 * WB_ROW; i += 256) wB_l[i] = wsu[WS_WB + i];
  if (tid < 196) G_l[tid] = wsf[WS_G + tid];
  __syncthreads();

  // fragment geometry: A row = (sample, m), k-slice kg = lane>>4
  const int row = lane & 15;
  const int kg = lane >> 4;
  const int m = row & 7;
  const int b0 = blockIdx.x * 8 + wid * 2;  // this wave's 2 samples
  const float* xg = x + (size_t)b0 * 4096;  // sample b0 base
  float* xw = xs + wid * XW;                // this wave's LDS region

  // LDS linear [slot][256]; lane reads t-th element at j = t^kg:
  // addr = kg*64 + 8*(t^kg) + m -> banks 8*((t^kg)&3)+m = all 32, 2-way free
  const float* xr2 = xw + (row >> 3) * 256 + kg * 64 + m;
  const unsigned int* wrow = wB_l + row * WB_ROW;
  int jo[8];
#pragma unroll
  for (int t = 0; t < 8; ++t) jo[t] = 8 * (t ^ kg);

  // hoist the y read (latency hides under the K-loop)
  const int yv = (lane < 28) ? y[b0 * 14 + lane] : 0;

  // prime the 2-chunk-deep DMA pipeline (chunks 0,1): 2 linear DMAs/chunk
#pragma unroll
  for (int c = 0; c < 2; ++c)
#pragma unroll
    for (int sl = 0; sl < 2; ++sl)
      dma16nt(xg + sl * 4096 + c * 256 + lane * 4, xw + c * XBUF + sl * 256);

  v4f acc = {0.f, 0.f, 0.f, 0.f};   // dot C-tile
  v4f acc2 = {0.f, 0.f, 0.f, 0.f};  // Gram C-tile (A*A^T)
  float q = 0.f;                    // fp32 sum u^2 (this lane's slice)

#pragma unroll
  for (int ch = 0; ch < NCH; ++ch) {
    const int buf = ch & 1;
    // wait for chunk ch's 2 DMAs (oldest); keep chunk ch+1's in flight
    if (ch == NCH - 1)
      asm volatile("s_waitcnt vmcnt(0)" ::: "memory");
    else
      asm volatile("s_waitcnt vmcnt(2)" ::: "memory");

    float u[8];
    const float* xb = xr2 + buf * XBUF;
#pragma unroll
    for (int t = 0; t < 8; ++t) u[t] = xb[jo[t]];
    const s8v bfrag = *(const s8v*)(wrow + ch * 16 + kg * 4);
#pragma unroll
    for (int t = 0; t < 8; ++t) q = fmaf(u[t], u[t], q);
    APk a;
#pragma unroll
    for (int jj = 0; jj < 4; ++jj)
      CVT_PK_BF16(a.i[jj], u[2 * jj], u[2 * jj + 1]);

    // refill this buffer with chunk ch+2 (in-wave WAR: drain ds_reads first)
    if (ch < NCH - 2) {
      asm volatile("s_waitcnt lgkmcnt(0)" ::: "memory");
#pragma unroll
      for (int sl = 0; sl < 2; ++sl)
        dma16nt(xg + sl * 4096 + (ch + 2) * 256 + lane * 4,
                xw + buf * XBUF + sl * 256);
    }

    acc = __builtin_amdgcn_mfma_f32_16x16x32_bf16(a.s, bfrag, acc, 0, 0, 0);
    acc2 = __builtin_amdgcn_mfma_f32_16x16x32_bf16(a.s, a.s, acc2, 0, 0, 0);
  }

  // ---- stage P mask for the wave's 2 samples (same-wave, no barrier) ----
  if (lane < 28) {
    const int s = (lane >= 14) ? 1 : 0;
    P_l[wid][s][lane - s * 14] = (yv == 1) ? 1.f : 0.f;
  }

  // ---- dot tail: max over m (C layout: col=lane&15, row=kg*4+reg) ----
  float dmax = fmaxf(fmaxf(acc[0], acc[1]), fmaxf(acc[2], acc[3]));
  dmax = fmaxf(dmax, swz_f<0x401F>(dmax));  // xor16: combine kg pairs
  if ((lane & 16) == 0 && (lane & 15) < 14)
    dots_l[wid][lane >> 5][lane & 15] = dmax;

  // ---- Gram tail: per-sample 8x8 block sum (for l1) ----
  const float loc2 = acc2[0] + acc2[1] + acc2[2] + acc2[3];
  const bool validb = (((lane & 15) < 8) == (lane < 32));
  float s2v = validb ? loc2 : 0.f;
  float q2 = q + shfl_x32(q);
  float qv = validb ? q2 : 0.f;

  asm volatile("s_waitcnt lgkmcnt(0)" ::: "memory");  // dots/P visible in-wave

  // ---- pair phase: lanes 0-31 do b0's 196 pairs, lanes 32-63 do b1's ----
  const int half = lane >> 5;
  const int hl = lane & 31;
  const float* dp = dots_l[wid][half];
  const float* Pp = P_l[wid][half];
  float S = 0.f, Gc = 0.f;
#pragma unroll
  for (int r = 0; r < 7; ++r) {
    const int tt = r * 28 + hl;
    if (hl < 28) {
      const int p = (tt * 2341) >> 15;  // tt/14, exact for tt<196
      const int n = tt - p * 14;
      const float Ppv = Pp[p], Pnv = Pp[n];
      S += Ppv * (1.f - Pnv) * softplus_f(dp[n] - dp[p]);
      Gc = fmaf(Ppv * Pnv, G_l[tt], Gc);
    }
  }
  float npv = (hl < 14) ? Pp[hl] : 0.f;
  float w2v = (hl < 14) ? Pp[hl] * G_l[hl * 15] : 0.f;  // P[c]*G[c][c]

  // ---- six half-reductions: lane31 = b0 totals, lane63 = b1 totals ----
  S = hsum32(S);
  Gc = hsum32(Gc);
  s2v = hsum32(s2v);
  qv = hsum32(qv);
  npv = hsum32(npv);
  w2v = hsum32(w2v);

  float loss = 0.f;
  if ((lane & 31) == 31) {
    const float npos = npv;
    const float base = S / npos;  // nneg>=1 guaranteed (y[:,-1]=0)
    const float tv =
        (npos > 1.5f) ? (w2v - Gc / npos) / (npos - 1.f) : 0.f;
    // l1 = sum_e sig2 (var >= 0) = (sum u^2 - (1/8) sum_e t^2)/7
    const float l1 = (qv - s2v * 0.125f) * (1.f / 7.f);
    loss = 1.4f * (1.f + tv) * base + 0.6f * l1;  // 2*((1-b)(1+tv)base + b*l1)
  }
  loss += shfl_x32(loss);  // lane31 = b0+b1
  if (lane == 31) atomicAdd(&slots[blockIdx.x & (NSLOTS - 1)], loss);
}

// ---- finalize (1 wave): sum the 256 slots -> out[0] ----
__global__ void MID_LOSS_fin(const float* __restrict__ wsf,
                             float* __restrict__ out) {
  const int tid = threadIdx.x;  // 64 threads
  float s = wsf[tid] + wsf[tid + 64] + wsf[tid + 128] + wsf[tid + 192];
  s = wsum64(s);
  if (tid == 63) out[0] = s * (1.f / (float)BATCH);
}

extern "C" void kernel_launch(void* const* d_in, const int* in_sizes, int n_in,
                              void* d_out, int out_size, void* d_ws, size_t ws_size,
                              hipStream_t stream) {
  const float* x = (const float*)d_in[0];
  const int* y = (const int*)d_in[1];
  const float* w = (const float*)d_in[2];
  float* out = (float*)d_out;
  float* wsf = (float*)d_ws;

  MID_LOSS_prep<<<1, 256, 0, stream>>>(w, wsf);
  MID_LOSS_main<<<NBLK, 256, 0, stream>>>(x, y, wsf, wsf);
  MID_LOSS_fin<<<1, 64, 0, stream>>>(wsf, out);
}